// Round 12
// baseline (405.726 us; speedup 1.0000x reference)
//
#include <hip/hip_runtime.h>

typedef unsigned short u16;
typedef __attribute__((ext_vector_type(8))) short short8;
typedef __attribute__((ext_vector_type(4))) float f32x4;

#define D_DIM   1024
#define ROWS    32768   // B*T = 4*8192
#define T_DIM   8192

__device__ __forceinline__ float bf2f(u16 u) {
    union { unsigned int i; float f; } c; c.i = ((unsigned int)u) << 16; return c.f;
}
__device__ __forceinline__ u16 f2bf(float f) {
    union { float f; unsigned int i; } c; c.f = f;
    unsigned int r = c.i + 0x7FFF + ((c.i >> 16) & 1);   // RNE
    return (u16)(r >> 16);
}

#define GLL16(gp, lp) \
    __builtin_amdgcn_global_load_lds((const __attribute__((address_space(1))) void*)(gp), \
                                     (__attribute__((address_space(3))) void*)(lp), 16, 0, 0)

// ---------------- Kernel 0: x fp32 -> xb bf16 ----------------
__global__ void convert_x(const float* __restrict__ x, u16* __restrict__ xb) {
    size_t idx = ((size_t)blockIdx.x * 256 + threadIdx.x) * 8;
    float4 f0 = *reinterpret_cast<const float4*>(x + idx);
    float4 f1 = *reinterpret_cast<const float4*>(x + idx + 4);
    short8 v;
    v[0] = (short)f2bf(f0.x); v[1] = (short)f2bf(f0.y);
    v[2] = (short)f2bf(f0.z); v[3] = (short)f2bf(f0.w);
    v[4] = (short)f2bf(f1.x); v[5] = (short)f2bf(f1.y);
    v[6] = (short)f2bf(f1.z); v[7] = (short)f2bf(f1.w);
    *reinterpret_cast<short8*>(xb + idx) = v;
}

// ---------------- Kernel 1: convert+transpose Wqkv (1024x3072 fp32) -> WT (3072x1024 bf16) ----
__global__ void transpose_w(const float* __restrict__ W, u16* __restrict__ WT) {
    __shared__ u16 tile[32][34];
    int nb = blockIdx.x * 32;
    int kb = blockIdx.y * 32;
    int tx = threadIdx.x;   // 0..31
    int ty = threadIdx.y;   // 0..7
    #pragma unroll
    for (int i = 0; i < 32; i += 8)
        tile[ty + i][tx] = f2bf(W[(size_t)(kb + ty + i) * 3072 + nb + tx]);
    __syncthreads();
    #pragma unroll
    for (int i = 0; i < 32; i += 8)
        WT[(size_t)(nb + ty + i) * D_DIM + kb + tx] = tile[tx][ty + i];
}

// ---------------- Kernel 2: 8-phase GEMM, 256x256, BK=64, dbuf-2 (WAR-FIXED) ----
// C[row, col] = sum_k xb[row,k] * WT[col,k] + bqkv[col]
// r11 failed (absmax 3.54) from a WAR race: A-halves are owned by WAVE GROUPS
// (wm=0 reads only A-lo in ph1 AND ph3; wm=1 only A-hi) — so A-lo is live through
// ph3, but r11 staged next-tile A-lo at ph2. FIX: A-lo staging moved ph2->ph4,
// ph6->ph8. Corrected stage schedule (each half-tile staged strictly after its
// last reader's close barrier):
//   ph1: A-hi->buf1 (buf1 A-hi last read prev ph7)   ph5: A-hi->buf0 (ph3)
//   ph2: —                                           ph6: —
//   ph3: B-lo->buf0 (ph2)                            ph7: B-lo->buf1 (ph6)
//   ph4: A-lo->buf0 (ph3) + B-hi->buf0 (ph2)         ph8: A-lo->buf1 (ph7) + B-hi->buf1 (ph6)
// vmcnt ledger: entering ph1 with 6 outstanding (next-odd's {B-lo,A-lo,B-hi});
// ph1(+2) ph3(+2) ph4(+4) -> 14; ph4 vmcnt(6) drains 8 oldest = odd tile's 4
// half-tiles -> certified for ph5-8. ph5(+2) ph7(+2) ph8(+4) -> 14; ph8 vmcnt(6)
// drains next-even's 4 -> certified for next ph1-4. Symmetric; never 0 till tail.
// Safety mechanism: reads complete before each phase's close barrier (compiler
// waitcnt + lgkmcnt(0) before MFMA); overwriting GLLs issue only after that
// barrier -> no read/write overlap. Phase bracket: reads+stage BEFORE open
// barrier; open barrier -> lgkmcnt(0) -> setprio(1) -> 16 MFMA -> setprio(0) ->
// [vmcnt(6) @ ph4/ph8] -> close barrier. NO sched_barrier (m141).
// Swizzle (r1, refcheck-passed @BK=64, 0 conflicts): 16B-slot g' = g ^ (row&7).

#define STAGE(P, BUF, SH, HALF) do {                                              \
    GLL16(P,        &SH[BUF][(HALF)*8192 + dstW]);                                \
    GLL16(P + 8192, &SH[BUF][(HALF)*8192 + dstW + 512]);                          \
    P += 64; } while (0)

#define RD_A(BUF, MH)                                                             \
    _Pragma("unroll")                                                             \
    for (int mi = 0; mi < 4; ++mi) {                                              \
        aF[mi][0] = *reinterpret_cast<const short8*>(&a_sh[BUF][aRdB + ((MH)*4+mi)*1024 + gq0]); \
        aF[mi][1] = *reinterpret_cast<const short8*>(&a_sh[BUF][aRdB + ((MH)*4+mi)*1024 + gq1]); \
    }

#define RD_B(BUF, NH, DST)                                                        \
    _Pragma("unroll")                                                             \
    for (int nt = 0; nt < 2; ++nt) {                                              \
        DST[nt][0] = *reinterpret_cast<const short8*>(&b_sh[BUF][bRdB + ((NH)*2+nt)*1024 + gq0]); \
        DST[nt][1] = *reinterpret_cast<const short8*>(&b_sh[BUF][bRdB + ((NH)*2+nt)*1024 + gq1]); \
    }

#define MM(MH, NH, B)                                                             \
    _Pragma("unroll")                                                             \
    for (int ks = 0; ks < 2; ++ks)                                                \
        _Pragma("unroll")                                                         \
        for (int mi = 0; mi < 4; ++mi)                                            \
            _Pragma("unroll")                                                     \
            for (int nt = 0; nt < 2; ++nt)                                        \
                acc[(MH)*4+mi][(NH)*2+nt] = __builtin_amdgcn_mfma_f32_16x16x32_bf16( \
                    aF[mi][ks], B[nt][ks], acc[(MH)*4+mi][(NH)*2+nt], 0, 0, 0)

#define OPENB do { __builtin_amdgcn_s_barrier();                                  \
    asm volatile("s_waitcnt lgkmcnt(0)" ::: "memory");                            \
    __builtin_amdgcn_s_setprio(1); } while (0)
#define CLOSE do { __builtin_amdgcn_s_setprio(0);                                 \
    __builtin_amdgcn_s_barrier(); } while (0)
#define CLOSE_VM6 do { __builtin_amdgcn_s_setprio(0);                             \
    asm volatile("s_waitcnt vmcnt(6)" ::: "memory");                              \
    __builtin_amdgcn_s_barrier(); } while (0)
#define CLOSE_VM0 do { __builtin_amdgcn_s_setprio(0);                             \
    asm volatile("s_waitcnt vmcnt(0)" ::: "memory");                              \
    __builtin_amdgcn_s_barrier(); } while (0)

__global__ __launch_bounds__(512, 1)
void gemm_k(const u16* __restrict__ xb, const u16* __restrict__ WT,
            const float* __restrict__ bqkv,
            u16* __restrict__ qb, u16* __restrict__ kvb,
            float* __restrict__ qssq, float* __restrict__ kssq)
{
    // dbuf-2: each buffer = 256 rows x 64 k u16 = 32 KB per operand; 128 KiB total.
    // Halves: rows 0..127 (lo, u16 off 0..8191), rows 128..255 (hi, 8192..16383).
    __shared__ __align__(16) u16 a_sh[2][16384];
    __shared__ __align__(16) u16 b_sh[2][16384];

    const int tid  = threadIdx.x;
    const int lane = tid & 63;
    const int w    = tid >> 6;      // wave 0..7
    const int l15  = lane & 15;
    const int quad = lane >> 4;     // 0..3
    const int wm   = w >> 2;        // 0..1  (M half)
    const int wn   = w & 3;         // 0..3  (N quarter)

    // bijective XCD swizzle: 1536 blocks, 192 contiguous (bx,by) per XCD
    const int flat = blockIdx.x;
    const int swz  = (flat & 7) * 192 + (flat >> 3);
    const int bx   = swz & 127;     // 0..127 (M)
    const int by   = swz >> 7;      // 0..11  (N)
    const int r0   = bx * 256;
    const int c0   = by * 256;

    // ---- staging addresses ----
    // Half-tile = 128 rows x 64 k = 16 KB = 512 thr x 2 GLL x 16B. Thread's 16B slot
    // s = w*128 + i*64 + lane -> row_local = w*16 + i*8 + (lane>>3), g' = lane&7;
    // source k-group gsrc = g' ^ (row&7) = (lane&7) ^ ((lane>>3)&7)  (per-thread const).
    const int rowL = w * 16 + (lane >> 3);               // i=0 local row (0..127)
    const int gsrc = (lane & 7) ^ ((lane >> 3) & 7);
    const u16* pALo = xb + (size_t)(r0 + rowL) * 1024 + gsrc * 8;
    const u16* pAHi = xb + (size_t)(r0 + 128 + rowL) * 1024 + gsrc * 8;
    const u16* pBLo = WT + (size_t)(c0 + rowL) * 1024 + gsrc * 8;
    const u16* pBHi = WT + (size_t)(c0 + 128 + rowL) * 1024 + gsrc * 8;
    // i=1 source = +8 rows = +8192 u16 (folded in STAGE). Wave-uniform LDS dest:
    const int dstW = w * 1024;      // + half*8192 + i*512 (u16 idx)

    // ---- fragment read offsets (u16 index within a buffer) ----
    // row = base + l15 (base mult of 16) -> row&7 = l15&7. k-group G = quad + 4*ks.
    const int gq0  = ((quad)     ^ (l15 & 7)) * 8;   // ks = 0
    const int gq1  = ((quad + 4) ^ (l15 & 7)) * 8;   // ks = 1
    const int aRdB = (wm * 128 + l15) * 64;          // + (mh*4+mi)*1024
    const int bRdB = (wn * 64 + l15) * 64;           // + (nh*2+nt)*1024

    f32x4 acc[8][4];
    #pragma unroll
    for (int mi = 0; mi < 8; ++mi)
        #pragma unroll
        for (int nt = 0; nt < 4; ++nt) acc[mi][nt] = (f32x4)(0.0f);

    short8 aF[4][2], bLo[2][2], bHi[2][2];

    // ---- prologue: 7 half-tiles ----
    STAGE(pALo, 0, a_sh, 0);   // A-lo t0
    STAGE(pBLo, 0, b_sh, 0);   // B-lo t0
    STAGE(pBHi, 0, b_sh, 1);   // B-hi t0
    STAGE(pAHi, 0, a_sh, 1);   // A-hi t0
    STAGE(pALo, 1, a_sh, 0);   // A-lo t1
    STAGE(pBLo, 1, b_sh, 0);   // B-lo t1
    STAGE(pBHi, 1, b_sh, 1);   // B-hi t1
    asm volatile("s_waitcnt vmcnt(6)" ::: "memory");   // tile 0 fully resident
    __builtin_amdgcn_s_barrier();

    // ---- main loop: iterations over tile pairs (t=2it in buf0, t+1 in buf1) ----
    #pragma unroll 1
    for (int it = 0; it < 7; ++it) {
        // ph1: Q(0,0) even tile; stage A-hi of odd tile -> buf1
        RD_A(0, 0); RD_B(0, 0, bLo); STAGE(pAHi, 1, a_sh, 1);
        OPENB; MM(0, 0, bLo); CLOSE;
        // ph2: Q(0,1); no stage (A-lo buf0 still live until ph3)
        RD_B(0, 1, bHi);
        OPENB; MM(0, 1, bHi); CLOSE;
        // ph3: Q(1,0); stage B-lo next even -> buf0
        RD_A(0, 1); STAGE(pBLo, 0, b_sh, 0);
        OPENB; MM(1, 0, bLo); CLOSE;
        // ph4: Q(1,1); stage A-lo + B-hi next even -> buf0; counted wait
        STAGE(pALo, 0, a_sh, 0); STAGE(pBHi, 0, b_sh, 1);
        OPENB; MM(1, 1, bHi); CLOSE_VM6;
        // ph5: Q(0,0) odd tile; stage A-hi next even -> buf0
        RD_A(1, 0); RD_B(1, 0, bLo); STAGE(pAHi, 0, a_sh, 1);
        OPENB; MM(0, 0, bLo); CLOSE;
        // ph6: Q(0,1); no stage (A-lo buf1 live until ph7)
        RD_B(1, 1, bHi);
        OPENB; MM(0, 1, bHi); CLOSE;
        // ph7: Q(1,0); stage B-lo next odd -> buf1
        RD_A(1, 1); STAGE(pBLo, 1, b_sh, 0);
        OPENB; MM(1, 0, bLo); CLOSE;
        // ph8: Q(1,1); stage A-lo + B-hi next odd -> buf1; counted wait
        STAGE(pALo, 1, a_sh, 0); STAGE(pBHi, 1, b_sh, 1);
        OPENB; MM(1, 1, bHi); CLOSE_VM6;
    }
    // ---- tail: tiles 14 (buf0), 15 (buf1); only A-hi_15 still to stage ----
    RD_A(0, 0); RD_B(0, 0, bLo); STAGE(pAHi, 1, a_sh, 1);
    OPENB; MM(0, 0, bLo); CLOSE;
    RD_B(0, 1, bHi);
    OPENB; MM(0, 1, bHi); CLOSE;
    RD_A(0, 1);
    OPENB; MM(1, 0, bLo); CLOSE;
    OPENB; MM(1, 1, bHi); CLOSE_VM0;   // drains A-hi_15 -> t15 resident
    RD_A(1, 0); RD_B(1, 0, bLo);
    OPENB; MM(0, 0, bLo); CLOSE;
    RD_B(1, 1, bHi);
    OPENB; MM(0, 1, bHi); CLOSE;
    RD_A(1, 1);
    OPENB; MM(1, 0, bLo); CLOSE;
    OPENB; MM(1, 1, bHi); CLOSE;

    // ---- epilogue: bias ----
    float bcol[4];
    #pragma unroll
    for (int nt = 0; nt < 4; ++nt)
        bcol[nt] = bqkv[c0 + wn * 64 + nt * 16 + l15];
    #pragma unroll
    for (int mi = 0; mi < 8; ++mi)
        #pragma unroll
        for (int nt = 0; nt < 4; ++nt)
            #pragma unroll
            for (int rg = 0; rg < 4; ++rg) acc[mi][nt][rg] += bcol[nt];

    // ---- row sum-of-squares (q and k blocks only) ----
    if (by < 8) {
        float* ssq = (by < 4) ? qssq : kssq;
        #pragma unroll
        for (int mi = 0; mi < 8; ++mi)
            #pragma unroll
            for (int rg = 0; rg < 4; ++rg) {
                float s = acc[mi][0][rg] * acc[mi][0][rg]
                        + acc[mi][1][rg] * acc[mi][1][rg]
                        + acc[mi][2][rg] * acc[mi][2][rg]
                        + acc[mi][3][rg] * acc[mi][3][rg];
                #pragma unroll
                for (int m = 1; m < 16; m <<= 1) s += __shfl_xor(s, m, 16);
                if (l15 == 0)
                    atomicAdd(&ssq[r0 + wm * 128 + mi * 16 + quad * 4 + rg], s);
            }
    }

    // ---- store bf16 ----
    u16* dst;
    int ldc, cb;
    if (by < 4) { dst = qb;  ldc = 1024; cb = c0; }
    else        { dst = kvb; ldc = 2048; cb = c0 - 1024; }
    #pragma unroll
    for (int mi = 0; mi < 8; ++mi)
        #pragma unroll
        for (int nt = 0; nt < 4; ++nt) {
            int col = cb + wn * 64 + nt * 16 + l15;
            #pragma unroll
            for (int rg = 0; rg < 4; ++rg) {
                int row = r0 + wm * 128 + mi * 16 + quad * 4 + rg;
                dst[(size_t)row * ldc + col] = f2bf(acc[mi][nt][rg]);
            }
        }
}

// ---------------- Kernel 3: kv[b,d] = sum_t k*v*rsqrt(kssq) ----------------
__global__ void kv_reduce(const u16* __restrict__ kvb, const float* __restrict__ kssq,
                          float* __restrict__ kv)
{
    int d  = threadIdx.x * 8;                  // 128 threads cover 1024 d
    int b  = blockIdx.y;                       // 0..3
    int t0 = blockIdx.x * 64;                  // 128 t-chunks of 64 rows
    float a[8];
    #pragma unroll
    for (int e = 0; e < 8; ++e) a[e] = 0.0f;
    for (int r = 0; r < 64; ++r) {
        int row = b * T_DIM + t0 + r;
        float kin = rsqrtf(kssq[row]);
        short8 k8 = *reinterpret_cast<const short8*>(kvb + (size_t)row * 2048 + d);
        short8 v8 = *reinterpret_cast<const short8*>(kvb + (size_t)row * 2048 + 1024 + d);
        #pragma unroll
        for (int e = 0; e < 8; ++e)
            a[e] += bf2f((u16)k8[e]) * bf2f((u16)v8[e]) * kin;
    }
    #pragma unroll
    for (int e = 0; e < 8; ++e)
        atomicAdd(&kv[b * D_DIM + d + e], a[e]);
}

// ---------------- Kernel 4: out = q*rsqrt(qssq)*kv*scale + bias (fp32) ----------------
__global__ void finalize(const u16* __restrict__ qb, const float* __restrict__ qssq,
                         const float* __restrict__ kv, const float* __restrict__ scale,
                         const float* __restrict__ bias, float* __restrict__ out)
{
    size_t idx = (size_t)blockIdx.x * 256 + threadIdx.x;   // vec8 index
    int row = (int)(idx >> 7);
    int dv  = ((int)idx & 127) * 8;
    int b   = row >> 13;
    float qi = rsqrtf(qssq[row]);
    short8 qv = *reinterpret_cast<const short8*>(qb + (size_t)row * D_DIM + dv);
    const float* kvp = kv + b * D_DIM + dv;
    const float* sp  = scale + dv;
    const float* bp  = bias + dv;
    float4 o0, o1;
    o0.x = bf2f((u16)qv[0]) * qi * kvp[0] * sp[0] + bp[0];
    o0.y = bf2f((u16)qv[1]) * qi * kvp[1] * sp[1] + bp[1];
    o0.z = bf2f((u16)qv[2]) * qi * kvp[2] * sp[2] + bp[2];
    o0.w = bf2f((u16)qv[3]) * qi * kvp[3] * sp[3] + bp[3];
    o1.x = bf2f((u16)qv[4]) * qi * kvp[4] * sp[4] + bp[4];
    o1.y = bf2f((u16)qv[5]) * qi * kvp[5] * sp[5] + bp[5];
    o1.z = bf2f((u16)qv[6]) * qi * kvp[6] * sp[6] + bp[6];
    o1.w = bf2f((u16)qv[7]) * qi * kvp[7] * sp[7] + bp[7];
    float* op = out + (size_t)row * D_DIM + dv;
    *reinterpret_cast<float4*>(op)     = o0;
    *reinterpret_cast<float4*>(op + 4) = o1;
}

extern "C" void kernel_launch(void* const* d_in, const int* in_sizes, int n_in,
                              void* d_out, int out_size, void* d_ws, size_t ws_size,
                              hipStream_t stream) {
    const float* x     = (const float*)d_in[0];
    const float* W     = (const float*)d_in[1];
    const float* bqkv  = (const float*)d_in[2];
    const float* scale = (const float*)d_in[3];
    const float* bias  = (const float*)d_in[4];
    float* out = (float*)d_out;

    // d_out doubles as scratch until finalize: xb (64 MB) + WT (6 MB) < 128 MB
    u16* xb = (u16*)d_out;
    u16* WT = (u16*)((char*)d_out + 67108864);

    char* ws = (char*)d_ws;
    u16*   qb   = (u16*)ws;                         //  67,108,864 B
    u16*   kvb  = (u16*)(ws + 67108864);            // 134,217,728 B
    float* qssq = (float*)(ws + 201326592);         //     131,072 B
    float* kssq = (float*)(ws + 201457664);         //     131,072 B
    float* kv   = (float*)(ws + 201588736);         //      16,384 B

    convert_x  <<<dim3(ROWS * D_DIM / 8 / 256), dim3(256), 0, stream>>>(x, xb);
    transpose_w<<<dim3(96, 32), dim3(32, 8), 0, stream>>>(W, WT);
    hipMemsetAsync(qssq, 0, 131072 + 131072 + 16384, stream);
    gemm_k     <<<dim3(1536), dim3(512), 0, stream>>>(xb, WT, bqkv, qb, kvb, qssq, kssq);
    kv_reduce  <<<dim3(T_DIM / 64, 4), dim3(128), 0, stream>>>(kvb, kssq, kv);
    finalize   <<<dim3(ROWS * (D_DIM / 8) / 256), dim3(256), 0, stream>>>(qb, qssq, kv, scale, bias, out);
}

// Round 13
// 363.195 us; speedup vs baseline: 1.1171x; 1.1171x over previous
//
#include <hip/hip_runtime.h>

typedef unsigned short u16;
typedef __attribute__((ext_vector_type(8))) short short8;
typedef __attribute__((ext_vector_type(4))) float f32x4;

#define D_DIM   1024
#define ROWS    32768   // B*T = 4*8192
#define T_DIM   8192

__device__ __forceinline__ float bf2f(u16 u) {
    union { unsigned int i; float f; } c; c.i = ((unsigned int)u) << 16; return c.f;
}
__device__ __forceinline__ u16 f2bf(float f) {
    union { float f; unsigned int i; } c; c.f = f;
    unsigned int r = c.i + 0x7FFF + ((c.i >> 16) & 1);   // RNE
    return (u16)(r >> 16);
}

#define GLL16(gp, lp) \
    __builtin_amdgcn_global_load_lds((const __attribute__((address_space(1))) void*)(gp), \
                                     (__attribute__((address_space(3))) void*)(lp), 16, 0, 0)

// ---------------- Kernel 0: x fp32 -> xb bf16 ----------------
__global__ void convert_x(const float* __restrict__ x, u16* __restrict__ xb) {
    size_t idx = ((size_t)blockIdx.x * 256 + threadIdx.x) * 8;
    float4 f0 = *reinterpret_cast<const float4*>(x + idx);
    float4 f1 = *reinterpret_cast<const float4*>(x + idx + 4);
    short8 v;
    v[0] = (short)f2bf(f0.x); v[1] = (short)f2bf(f0.y);
    v[2] = (short)f2bf(f0.z); v[3] = (short)f2bf(f0.w);
    v[4] = (short)f2bf(f1.x); v[5] = (short)f2bf(f1.y);
    v[6] = (short)f2bf(f1.z); v[7] = (short)f2bf(f1.w);
    *reinterpret_cast<short8*>(xb + idx) = v;
}

// ---------------- Kernel 1: convert+transpose Wqkv (1024x3072 fp32) -> WT (3072x1024 bf16) ----
__global__ void transpose_w(const float* __restrict__ W, u16* __restrict__ WT) {
    __shared__ u16 tile[32][34];
    int nb = blockIdx.x * 32;
    int kb = blockIdx.y * 32;
    int tx = threadIdx.x;   // 0..31
    int ty = threadIdx.y;   // 0..7
    #pragma unroll
    for (int i = 0; i < 32; i += 8)
        tile[ty + i][tx] = f2bf(W[(size_t)(kb + ty + i) * 3072 + nb + tx]);
    __syncthreads();
    #pragma unroll
    for (int i = 0; i < 32; i += 8)
        WT[(size_t)(nb + ty + i) * D_DIM + kb + tx] = tile[tx][ty + i];
}

// ---------------- Kernel 2: r4 GEMM structure + paired k/v column partition ----
// C[row, col] = sum_k xb[row,k] * WT[col,k] + bqkv[col]
// GEMM schedule = EXACT round-4/round-9 structure (session best, twice-reproduced:
// 250us, MfmaUtil 36.7, 0 conflicts, VGPR 108). The 8-phase port was falsified 3x
// (r5/r12: correct but 273-291us) — schedule held fixed from here on.
// NEW (orthogonal, non-schedule): paired k/v partition for by>=4. Block by owns
//   by<4 : q cols   [by*256, +256)                     -> qb + qssq (unchanged)
//   by>=4: k cols K0=[1024+(by-4)*128, +128) AND v cols V0=K0+1024 (matched slices).
// B-tile LDS row r (=output col r): wn_r=r>>6, cs=r&63; global WT row =
//   cs<32 ? K0+wn_r*32+cs : V0+wn_r*32+(cs-32).
// Fragment reads/swizzle/MFMA untouched; only the B staging source pointers remap.
// Thread fragment col nt in {0,1} = k value, nt in {2,3} = the SAME column's v value
// (col cs=nt*16+l15: nt<2 -> cs<32 k-half; nt-2 gives matching v) -> epilogue stores
// p[t,d] = (k+bk)*(v+bv) as bf16 (64 MB) instead of k,v (128 MB); kv_reduce reads
// half the bytes. Precision: one rounding of the f32 product vs two roundings before.
// kssq partials: 8 blocks x 128 k-cols (nt 0,1) = 1024 cols total, same as before.

#define SLOT(RING, SRING, STG, VM) do {                                           \
    short8 bF[4], aF[8];                                                          \
    _Pragma("unroll")                                                             \
    for (int nt = 0; nt < 4; ++nt)                                                \
        bF[nt] = *reinterpret_cast<const short8*>(&b_sh[RING][bRd + nt * 512]);   \
    _Pragma("unroll")                                                             \
    for (int mi = 0; mi < 8; ++mi)                                                \
        aF[mi] = *reinterpret_cast<const short8*>(&a_sh[RING][aRd + mi * 512]);   \
    if (STG) {                                                                    \
        GLL16(aPtr0, &a_sh[SRING][aDst0]); GLL16(aPtr1, &a_sh[SRING][aDst1]);     \
        GLL16(bPtr0, &b_sh[SRING][aDst0]); GLL16(bPtr1, &b_sh[SRING][aDst1]);     \
        aPtr0 += 32; aPtr1 += 32; bPtr0 += 32; bPtr1 += 32;                       \
    }                                                                             \
    _Pragma("unroll")                                                             \
    for (int mi = 0; mi < 8; ++mi)                                                \
        _Pragma("unroll")                                                         \
        for (int nt = 0; nt < 4; ++nt)                                            \
            acc[mi][nt] = __builtin_amdgcn_mfma_f32_16x16x32_bf16(                \
                aF[mi], bF[nt], acc[mi][nt], 0, 0, 0);                            \
    __builtin_amdgcn_sched_barrier(0);                                            \
    if ((VM) == 8)      asm volatile("s_waitcnt vmcnt(8)" ::: "memory");          \
    else if ((VM) == 4) asm volatile("s_waitcnt vmcnt(4)" ::: "memory");          \
    else if ((VM) == 0) asm volatile("s_waitcnt vmcnt(0)" ::: "memory");          \
    __builtin_amdgcn_s_barrier();                                                 \
} while (0)

__global__ __launch_bounds__(512, 1)
void gemm_k(const u16* __restrict__ xb, const u16* __restrict__ WT,
            const float* __restrict__ bqkv,
            u16* __restrict__ qb, u16* __restrict__ pb,
            float* __restrict__ qssq, float* __restrict__ kssq)
{
    // 4-slot ring: each slot 256 rows x 32 k (u16) = 16 KB per operand; 128 KiB total
    __shared__ __align__(16) u16 a_sh[4][8192];
    __shared__ __align__(16) u16 b_sh[4][8192];

    const int tid  = threadIdx.x;
    const int lane = tid & 63;
    const int w    = tid >> 6;      // wave 0..7
    const int l15  = lane & 15;
    const int quad = lane >> 4;     // 0..3
    const int wm   = w >> 2;        // 0..1  (M half)
    const int wn   = w & 3;         // 0..3  (N quarter)

    // bijective XCD swizzle: 1536 blocks, 192 contiguous (bx,by) per XCD
    const int flat = blockIdx.x;
    const int swz  = (flat & 7) * 192 + (flat >> 3);
    const int bx   = swz & 127;     // 0..127 (M)
    const int by   = swz >> 7;      // 0..11  (N)
    const int r0   = bx * 256;
    const int c0   = by * 256;
    const int K0   = 1024 + (by - 4) * 128;   // k-col base (by>=4)
    const int V0   = K0 + 1024;               // matched v-col base

    // ---- staging addresses ----
    // thread stages 16B groups sidx = w*128 + i*64 + lane (i=0,1) per operand per slot.
    // sidx -> B-tile row = sidx>>2, g' = sidx&3; source k-group gsrc = g' ^ ((row>>1)&3).
    const int row0 = w * 32 + (lane >> 2);
    const int gsrc = (lane & 3) ^ ((lane >> 3) & 3);   // same for i=0,1 (rows differ by 16)
    const u16* aPtr0 = xb + (size_t)(r0 + row0) * D_DIM + gsrc * 8;
    const u16* aPtr1 = xb + (size_t)(r0 + row0 + 16) * D_DIM + gsrc * 8;
    // B source rows: q blocks linear; paired blocks via the k/v slice map.
    int srcB0, srcB1;
    if (by < 4) {
        srcB0 = c0 + row0;
        srcB1 = c0 + row0 + 16;
    } else {
        int rB0 = row0,     wn0 = rB0 >> 6, cs0 = rB0 & 63;
        int rB1 = row0 + 16, wn1 = rB1 >> 6, cs1 = rB1 & 63;
        srcB0 = (cs0 < 32) ? (K0 + wn0 * 32 + cs0) : (V0 + wn0 * 32 + cs0 - 32);
        srcB1 = (cs1 < 32) ? (K0 + wn1 * 32 + cs1) : (V0 + wn1 * 32 + cs1 - 32);
    }
    const u16* bPtr0 = WT + (size_t)srcB0 * D_DIM + gsrc * 8;
    const u16* bPtr1 = WT + (size_t)srcB1 * D_DIM + gsrc * 8;
    const int aDst0 = w * 1024;          // wave-uniform linear LDS dest (u16 idx)
    const int aDst1 = w * 1024 + 512;

    // ---- fragment read offsets (u16 index within a slot) ----
    // row = base + l15 (base mult of 16) -> (row>>1)&3 == (l15>>1)&3
    const int gq  = (quad ^ ((l15 >> 1) & 3)) * 8;
    const int aRd = (wm * 128 + l15) * 32 + gq;      // + mi*512, mi=0..7 (rows mi*16+l15)
    const int bRd = (wn * 64 + l15) * 32 + gq;       // + nt*512, nt=0..3

    f32x4 acc[8][4];
    #pragma unroll
    for (int mi = 0; mi < 8; ++mi)
        #pragma unroll
        for (int nt = 0; nt < 4; ++nt) acc[mi][nt] = (f32x4)(0.0f);

    // ---- prologue: stage slots 0,1,2 ----
    GLL16(aPtr0, &a_sh[0][aDst0]); GLL16(aPtr1, &a_sh[0][aDst1]);
    GLL16(bPtr0, &b_sh[0][aDst0]); GLL16(bPtr1, &b_sh[0][aDst1]);
    aPtr0 += 32; aPtr1 += 32; bPtr0 += 32; bPtr1 += 32;
    GLL16(aPtr0, &a_sh[1][aDst0]); GLL16(aPtr1, &a_sh[1][aDst1]);
    GLL16(bPtr0, &b_sh[1][aDst0]); GLL16(bPtr1, &b_sh[1][aDst1]);
    aPtr0 += 32; aPtr1 += 32; bPtr0 += 32; bPtr1 += 32;
    GLL16(aPtr0, &a_sh[2][aDst0]); GLL16(aPtr1, &a_sh[2][aDst1]);
    GLL16(bPtr0, &b_sh[2][aDst0]); GLL16(bPtr1, &b_sh[2][aDst1]);
    aPtr0 += 32; aPtr1 += 32; bPtr0 += 32; bPtr1 += 32;
    asm volatile("s_waitcnt vmcnt(8)" ::: "memory");   // slot 0 resident (own loads)
    __builtin_amdgcn_s_barrier();                      // ... for all waves

    // ---- main loop: slots 0..27; slot s reads ring s&3, stages ring (s+3)&3 ----
    #pragma unroll 1
    for (int it = 0; it < 7; ++it) {
        SLOT(0, 3, 1, 8);
        SLOT(1, 0, 1, 8);
        SLOT(2, 1, 1, 8);
        SLOT(3, 2, 1, 8);
    }
    // ---- tail: slots 28..31 ----
    SLOT(0, 3, 1, 8);    // 28: stages slot 31; end-wait certifies slot 29
    SLOT(1, 0, 0, 4);    // 29: end-wait certifies slot 30
    SLOT(2, 0, 0, 0);    // 30: end-wait certifies slot 31
    SLOT(3, 0, 0, -1);   // 31

    if (by < 4) {
        // ---- q path (unchanged): bias, qssq, store qb ----
        float bcol[4];
        #pragma unroll
        for (int nt = 0; nt < 4; ++nt)
            bcol[nt] = bqkv[c0 + wn * 64 + nt * 16 + l15];
        #pragma unroll
        for (int mi = 0; mi < 8; ++mi)
            #pragma unroll
            for (int nt = 0; nt < 4; ++nt)
                #pragma unroll
                for (int rg = 0; rg < 4; ++rg) acc[mi][nt][rg] += bcol[nt];

        #pragma unroll
        for (int mi = 0; mi < 8; ++mi)
            #pragma unroll
            for (int rg = 0; rg < 4; ++rg) {
                float s = acc[mi][0][rg] * acc[mi][0][rg]
                        + acc[mi][1][rg] * acc[mi][1][rg]
                        + acc[mi][2][rg] * acc[mi][2][rg]
                        + acc[mi][3][rg] * acc[mi][3][rg];
                #pragma unroll
                for (int m = 1; m < 16; m <<= 1) s += __shfl_xor(s, m, 16);
                if (l15 == 0)
                    atomicAdd(&qssq[r0 + wm * 128 + mi * 16 + quad * 4 + rg], s);
            }

        #pragma unroll
        for (int mi = 0; mi < 8; ++mi)
            #pragma unroll
            for (int nt = 0; nt < 4; ++nt) {
                int col = c0 + wn * 64 + nt * 16 + l15;
                #pragma unroll
                for (int rg = 0; rg < 4; ++rg) {
                    int row = r0 + wm * 128 + mi * 16 + quad * 4 + rg;
                    qb[(size_t)row * 1024 + col] = f2bf(acc[mi][nt][rg]);
                }
            }
    } else {
        // ---- paired k/v path: bias (per-col via map), kssq (k frags only), p store ----
        float bcol[4];
        #pragma unroll
        for (int nt = 0; nt < 4; ++nt)
            bcol[nt] = (nt < 2) ? bqkv[K0 + wn * 32 + nt * 16 + l15]
                                : bqkv[V0 + wn * 32 + (nt - 2) * 16 + l15];
        #pragma unroll
        for (int mi = 0; mi < 8; ++mi)
            #pragma unroll
            for (int nt = 0; nt < 4; ++nt)
                #pragma unroll
                for (int rg = 0; rg < 4; ++rg) acc[mi][nt][rg] += bcol[nt];

        // kssq partial: k fragments are nt 0,1 (128 k-cols per block, 8 blocks = 1024)
        #pragma unroll
        for (int mi = 0; mi < 8; ++mi)
            #pragma unroll
            for (int rg = 0; rg < 4; ++rg) {
                float s = acc[mi][0][rg] * acc[mi][0][rg]
                        + acc[mi][1][rg] * acc[mi][1][rg];
                #pragma unroll
                for (int m = 1; m < 16; m <<= 1) s += __shfl_xor(s, m, 16);
                if (l15 == 0)
                    atomicAdd(&kssq[r0 + wm * 128 + mi * 16 + quad * 4 + rg], s);
            }

        // p[t,d] = k*v (same thread: nt and nt+2 are the same column's k and v)
        #pragma unroll
        for (int mi = 0; mi < 8; ++mi)
            #pragma unroll
            for (int ntp = 0; ntp < 2; ++ntp) {
                int col = (by - 4) * 128 + wn * 32 + ntp * 16 + l15;
                #pragma unroll
                for (int rg = 0; rg < 4; ++rg) {
                    int row = r0 + wm * 128 + mi * 16 + quad * 4 + rg;
                    pb[(size_t)row * 1024 + col] =
                        f2bf(acc[mi][ntp][rg] * acc[mi][ntp + 2][rg]);
                }
            }
    }
}

// ---------------- Kernel 3: kv[b,d] = sum_t p[t,d]*rsqrt(kssq[t]) ----------------
__global__ void kv_reduce(const u16* __restrict__ pb, const float* __restrict__ kssq,
                          float* __restrict__ kv)
{
    int d  = threadIdx.x * 8;                  // 128 threads cover 1024 d
    int b  = blockIdx.y;                       // 0..3
    int t0 = blockIdx.x * 64;                  // 128 t-chunks of 64 rows
    float a[8];
    #pragma unroll
    for (int e = 0; e < 8; ++e) a[e] = 0.0f;
    for (int r = 0; r < 64; ++r) {
        int row = b * T_DIM + t0 + r;
        float kin = rsqrtf(kssq[row]);
        short8 p8 = *reinterpret_cast<const short8*>(pb + (size_t)row * 1024 + d);
        #pragma unroll
        for (int e = 0; e < 8; ++e)
            a[e] += bf2f((u16)p8[e]) * kin;
    }
    #pragma unroll
    for (int e = 0; e < 8; ++e)
        atomicAdd(&kv[b * D_DIM + d + e], a[e]);
}

// ---------------- Kernel 4: out = q*rsqrt(qssq)*kv*scale + bias (fp32) ----------------
__global__ void finalize(const u16* __restrict__ qb, const float* __restrict__ qssq,
                         const float* __restrict__ kv, const float* __restrict__ scale,
                         const float* __restrict__ bias, float* __restrict__ out)
{
    size_t idx = (size_t)blockIdx.x * 256 + threadIdx.x;   // vec8 index
    int row = (int)(idx >> 7);
    int dv  = ((int)idx & 127) * 8;
    int b   = row >> 13;
    float qi = rsqrtf(qssq[row]);
    short8 qv = *reinterpret_cast<const short8*>(qb + (size_t)row * D_DIM + dv);
    const float* kvp = kv + b * D_DIM + dv;
    const float* sp  = scale + dv;
    const float* bp  = bias + dv;
    float4 o0, o1;
    o0.x = bf2f((u16)qv[0]) * qi * kvp[0] * sp[0] + bp[0];
    o0.y = bf2f((u16)qv[1]) * qi * kvp[1] * sp[1] + bp[1];
    o0.z = bf2f((u16)qv[2]) * qi * kvp[2] * sp[2] + bp[2];
    o0.w = bf2f((u16)qv[3]) * qi * kvp[3] * sp[3] + bp[3];
    o1.x = bf2f((u16)qv[4]) * qi * kvp[4] * sp[4] + bp[4];
    o1.y = bf2f((u16)qv[5]) * qi * kvp[5] * sp[5] + bp[5];
    o1.z = bf2f((u16)qv[6]) * qi * kvp[6] * sp[6] + bp[6];
    o1.w = bf2f((u16)qv[7]) * qi * kvp[7] * sp[7] + bp[7];
    float* op = out + (size_t)row * D_DIM + dv;
    *reinterpret_cast<float4*>(op)     = o0;
    *reinterpret_cast<float4*>(op + 4) = o1;
}

extern "C" void kernel_launch(void* const* d_in, const int* in_sizes, int n_in,
                              void* d_out, int out_size, void* d_ws, size_t ws_size,
                              hipStream_t stream) {
    const float* x     = (const float*)d_in[0];
    const float* W     = (const float*)d_in[1];
    const float* bqkv  = (const float*)d_in[2];
    const float* scale = (const float*)d_in[3];
    const float* bias  = (const float*)d_in[4];
    float* out = (float*)d_out;

    // d_out doubles as scratch until finalize: xb (64 MB) + WT (6 MB) < 128 MB
    u16* xb = (u16*)d_out;
    u16* WT = (u16*)((char*)d_out + 67108864);

    char* ws = (char*)d_ws;
    u16*   qb   = (u16*)ws;                         //  67,108,864 B
    u16*   pb   = (u16*)(ws + 67108864);            //  67,108,864 B (k*v products)
    float* qssq = (float*)(ws + 134217728);         //     131,072 B
    float* kssq = (float*)(ws + 134348800);         //     131,072 B
    float* kv   = (float*)(ws + 134479872);         //      16,384 B

    convert_x  <<<dim3(ROWS * D_DIM / 8 / 256), dim3(256), 0, stream>>>(x, xb);
    transpose_w<<<dim3(96, 32), dim3(32, 8), 0, stream>>>(W, WT);
    hipMemsetAsync(qssq, 0, 131072 + 131072 + 16384, stream);
    gemm_k     <<<dim3(1536), dim3(512), 0, stream>>>(xb, WT, bqkv, qb, pb, qssq, kssq);
    kv_reduce  <<<dim3(T_DIM / 64, 4), dim3(128), 0, stream>>>(pb, kssq, kv);
    finalize   <<<dim3(ROWS * (D_DIM / 8) / 256), dim3(256), 0, stream>>>(qb, qssq, kv, scale, bias, out);
}

// Round 14
// 359.952 us; speedup vs baseline: 1.1272x; 1.0090x over previous
//
#include <hip/hip_runtime.h>

typedef unsigned short u16;
typedef __attribute__((ext_vector_type(8))) short short8;
typedef __attribute__((ext_vector_type(4))) float f32x4;

#define D_DIM   1024
#define ROWS    32768   // B*T = 4*8192
#define T_DIM   8192

__device__ __forceinline__ float bf2f(u16 u) {
    union { unsigned int i; float f; } c; c.i = ((unsigned int)u) << 16; return c.f;
}
__device__ __forceinline__ u16 f2bf(float f) {
    union { float f; unsigned int i; } c; c.f = f;
    unsigned int r = c.i + 0x7FFF + ((c.i >> 16) & 1);   // RNE
    return (u16)(r >> 16);
}

#define GLL16(gp, lp) \
    __builtin_amdgcn_global_load_lds((const __attribute__((address_space(1))) void*)(gp), \
                                     (__attribute__((address_space(3))) void*)(lp), 16, 0, 0)

// ---------------- Kernel 0 (fused prep): convert x, transpose W, zero accumulators ----
// blocks [0, 16384)           : x fp32 -> xb bf16 (vec8 per thread)
// blocks [16384, 16384+3072)  : Wqkv (1024x3072 fp32) -> WT (3072x1024 bf16) transpose
// blocks [19456, 19456+68)    : zero qssq|kssq|kv (278,528 B contiguous)
// All three are independent; stream order guarantees completion before gemm_k.
// Branch is block-uniform -> __syncthreads in the transpose path is safe.
__global__ __launch_bounds__(256)
void prep(const float* __restrict__ x, u16* __restrict__ xb,
          const float* __restrict__ W, u16* __restrict__ WT,
          float* __restrict__ zbase)
{
    const int bid = blockIdx.x;
    const int tid = threadIdx.x;
    __shared__ u16 tile[32][34];

    if (bid < 16384) {
        size_t idx = ((size_t)bid * 256 + tid) * 8;
        float4 f0 = *reinterpret_cast<const float4*>(x + idx);
        float4 f1 = *reinterpret_cast<const float4*>(x + idx + 4);
        short8 v;
        v[0] = (short)f2bf(f0.x); v[1] = (short)f2bf(f0.y);
        v[2] = (short)f2bf(f0.z); v[3] = (short)f2bf(f0.w);
        v[4] = (short)f2bf(f1.x); v[5] = (short)f2bf(f1.y);
        v[6] = (short)f2bf(f1.z); v[7] = (short)f2bf(f1.w);
        *reinterpret_cast<short8*>(xb + idx) = v;
    } else if (bid < 16384 + 3072) {
        int q  = bid - 16384;
        int nb = (q % 96) * 32;
        int kb = (q / 96) * 32;
        int tx = tid & 31;    // 0..31
        int ty = tid >> 5;    // 0..7
        #pragma unroll
        for (int i = 0; i < 32; i += 8)
            tile[ty + i][tx] = f2bf(W[(size_t)(kb + ty + i) * 3072 + nb + tx]);
        __syncthreads();
        #pragma unroll
        for (int i = 0; i < 32; i += 8)
            WT[(size_t)(nb + ty + i) * D_DIM + kb + tx] = tile[tx][ty + i];
    } else {
        int z = bid - (16384 + 3072);              // 0..67
        float4 zero = make_float4(0.f, 0.f, 0.f, 0.f);
        *reinterpret_cast<float4*>(zbase + ((size_t)z * 256 + tid) * 4) = zero;
    }
}

// ---------------- Kernel 2: r4 GEMM structure + paired k/v column partition ----
// (UNCHANGED from round 13 — session best: total 363us, gemm ~256us, 0 conflicts.)
// C[row, col] = sum_k xb[row,k] * WT[col,k] + bqkv[col]
// GEMM schedule = EXACT round-4/round-9 structure (twice-reproduced 250us; the
// 8-phase port was falsified 3x). Paired k/v partition for by>=4: block owns
// matched k-slice K0..K0+127 AND v-slice V0..V0+127; epilogue stores
// p[t,d] = (k+bk)*(v+bv) bf16 (64 MB) instead of k,v (128 MB).

#define SLOT(RING, SRING, STG, VM) do {                                           \
    short8 bF[4], aF[8];                                                          \
    _Pragma("unroll")                                                             \
    for (int nt = 0; nt < 4; ++nt)                                                \
        bF[nt] = *reinterpret_cast<const short8*>(&b_sh[RING][bRd + nt * 512]);   \
    _Pragma("unroll")                                                             \
    for (int mi = 0; mi < 8; ++mi)                                                \
        aF[mi] = *reinterpret_cast<const short8*>(&a_sh[RING][aRd + mi * 512]);   \
    if (STG) {                                                                    \
        GLL16(aPtr0, &a_sh[SRING][aDst0]); GLL16(aPtr1, &a_sh[SRING][aDst1]);     \
        GLL16(bPtr0, &b_sh[SRING][aDst0]); GLL16(bPtr1, &b_sh[SRING][aDst1]);     \
        aPtr0 += 32; aPtr1 += 32; bPtr0 += 32; bPtr1 += 32;                       \
    }                                                                             \
    _Pragma("unroll")                                                             \
    for (int mi = 0; mi < 8; ++mi)                                                \
        _Pragma("unroll")                                                         \
        for (int nt = 0; nt < 4; ++nt)                                            \
            acc[mi][nt] = __builtin_amdgcn_mfma_f32_16x16x32_bf16(                \
                aF[mi], bF[nt], acc[mi][nt], 0, 0, 0);                            \
    __builtin_amdgcn_sched_barrier(0);                                            \
    if ((VM) == 8)      asm volatile("s_waitcnt vmcnt(8)" ::: "memory");          \
    else if ((VM) == 4) asm volatile("s_waitcnt vmcnt(4)" ::: "memory");          \
    else if ((VM) == 0) asm volatile("s_waitcnt vmcnt(0)" ::: "memory");          \
    __builtin_amdgcn_s_barrier();                                                 \
} while (0)

__global__ __launch_bounds__(512, 1)
void gemm_k(const u16* __restrict__ xb, const u16* __restrict__ WT,
            const float* __restrict__ bqkv,
            u16* __restrict__ qb, u16* __restrict__ pb,
            float* __restrict__ qssq, float* __restrict__ kssq)
{
    // 4-slot ring: each slot 256 rows x 32 k (u16) = 16 KB per operand; 128 KiB total
    __shared__ __align__(16) u16 a_sh[4][8192];
    __shared__ __align__(16) u16 b_sh[4][8192];

    const int tid  = threadIdx.x;
    const int lane = tid & 63;
    const int w    = tid >> 6;      // wave 0..7
    const int l15  = lane & 15;
    const int quad = lane >> 4;     // 0..3
    const int wm   = w >> 2;        // 0..1  (M half)
    const int wn   = w & 3;         // 0..3  (N quarter)

    // bijective XCD swizzle: 1536 blocks, 192 contiguous (bx,by) per XCD
    const int flat = blockIdx.x;
    const int swz  = (flat & 7) * 192 + (flat >> 3);
    const int bx   = swz & 127;     // 0..127 (M)
    const int by   = swz >> 7;      // 0..11  (N)
    const int r0   = bx * 256;
    const int c0   = by * 256;
    const int K0   = 1024 + (by - 4) * 128;   // k-col base (by>=4)
    const int V0   = K0 + 1024;               // matched v-col base

    // ---- staging addresses ----
    const int row0 = w * 32 + (lane >> 2);
    const int gsrc = (lane & 3) ^ ((lane >> 3) & 3);   // same for i=0,1 (rows differ by 16)
    const u16* aPtr0 = xb + (size_t)(r0 + row0) * D_DIM + gsrc * 8;
    const u16* aPtr1 = xb + (size_t)(r0 + row0 + 16) * D_DIM + gsrc * 8;
    int srcB0, srcB1;
    if (by < 4) {
        srcB0 = c0 + row0;
        srcB1 = c0 + row0 + 16;
    } else {
        int rB0 = row0,      wn0 = rB0 >> 6, cs0 = rB0 & 63;
        int rB1 = row0 + 16, wn1 = rB1 >> 6, cs1 = rB1 & 63;
        srcB0 = (cs0 < 32) ? (K0 + wn0 * 32 + cs0) : (V0 + wn0 * 32 + cs0 - 32);
        srcB1 = (cs1 < 32) ? (K0 + wn1 * 32 + cs1) : (V0 + wn1 * 32 + cs1 - 32);
    }
    const u16* bPtr0 = WT + (size_t)srcB0 * D_DIM + gsrc * 8;
    const u16* bPtr1 = WT + (size_t)srcB1 * D_DIM + gsrc * 8;
    const int aDst0 = w * 1024;          // wave-uniform linear LDS dest (u16 idx)
    const int aDst1 = w * 1024 + 512;

    // ---- fragment read offsets (u16 index within a slot) ----
    const int gq  = (quad ^ ((l15 >> 1) & 3)) * 8;
    const int aRd = (wm * 128 + l15) * 32 + gq;      // + mi*512, mi=0..7
    const int bRd = (wn * 64 + l15) * 32 + gq;       // + nt*512, nt=0..3

    f32x4 acc[8][4];
    #pragma unroll
    for (int mi = 0; mi < 8; ++mi)
        #pragma unroll
        for (int nt = 0; nt < 4; ++nt) acc[mi][nt] = (f32x4)(0.0f);

    // ---- prologue: stage slots 0,1,2 ----
    GLL16(aPtr0, &a_sh[0][aDst0]); GLL16(aPtr1, &a_sh[0][aDst1]);
    GLL16(bPtr0, &b_sh[0][aDst0]); GLL16(bPtr1, &b_sh[0][aDst1]);
    aPtr0 += 32; aPtr1 += 32; bPtr0 += 32; bPtr1 += 32;
    GLL16(aPtr0, &a_sh[1][aDst0]); GLL16(aPtr1, &a_sh[1][aDst1]);
    GLL16(bPtr0, &b_sh[1][aDst0]); GLL16(bPtr1, &b_sh[1][aDst1]);
    aPtr0 += 32; aPtr1 += 32; bPtr0 += 32; bPtr1 += 32;
    GLL16(aPtr0, &a_sh[2][aDst0]); GLL16(aPtr1, &a_sh[2][aDst1]);
    GLL16(bPtr0, &b_sh[2][aDst0]); GLL16(bPtr1, &b_sh[2][aDst1]);
    aPtr0 += 32; aPtr1 += 32; bPtr0 += 32; bPtr1 += 32;
    asm volatile("s_waitcnt vmcnt(8)" ::: "memory");   // slot 0 resident (own loads)
    __builtin_amdgcn_s_barrier();                      // ... for all waves

    // ---- main loop: slots 0..27; slot s reads ring s&3, stages ring (s+3)&3 ----
    #pragma unroll 1
    for (int it = 0; it < 7; ++it) {
        SLOT(0, 3, 1, 8);
        SLOT(1, 0, 1, 8);
        SLOT(2, 1, 1, 8);
        SLOT(3, 2, 1, 8);
    }
    // ---- tail: slots 28..31 ----
    SLOT(0, 3, 1, 8);    // 28: stages slot 31; end-wait certifies slot 29
    SLOT(1, 0, 0, 4);    // 29: end-wait certifies slot 30
    SLOT(2, 0, 0, 0);    // 30: end-wait certifies slot 31
    SLOT(3, 0, 0, -1);   // 31

    if (by < 4) {
        // ---- q path: bias, qssq, store qb ----
        float bcol[4];
        #pragma unroll
        for (int nt = 0; nt < 4; ++nt)
            bcol[nt] = bqkv[c0 + wn * 64 + nt * 16 + l15];
        #pragma unroll
        for (int mi = 0; mi < 8; ++mi)
            #pragma unroll
            for (int nt = 0; nt < 4; ++nt)
                #pragma unroll
                for (int rg = 0; rg < 4; ++rg) acc[mi][nt][rg] += bcol[nt];

        #pragma unroll
        for (int mi = 0; mi < 8; ++mi)
            #pragma unroll
            for (int rg = 0; rg < 4; ++rg) {
                float s = acc[mi][0][rg] * acc[mi][0][rg]
                        + acc[mi][1][rg] * acc[mi][1][rg]
                        + acc[mi][2][rg] * acc[mi][2][rg]
                        + acc[mi][3][rg] * acc[mi][3][rg];
                #pragma unroll
                for (int m = 1; m < 16; m <<= 1) s += __shfl_xor(s, m, 16);
                if (l15 == 0)
                    atomicAdd(&qssq[r0 + wm * 128 + mi * 16 + quad * 4 + rg], s);
            }

        #pragma unroll
        for (int mi = 0; mi < 8; ++mi)
            #pragma unroll
            for (int nt = 0; nt < 4; ++nt) {
                int col = c0 + wn * 64 + nt * 16 + l15;
                #pragma unroll
                for (int rg = 0; rg < 4; ++rg) {
                    int row = r0 + wm * 128 + mi * 16 + quad * 4 + rg;
                    qb[(size_t)row * 1024 + col] = f2bf(acc[mi][nt][rg]);
                }
            }
    } else {
        // ---- paired k/v path: bias, kssq (k frags), store p = k*v ----
        float bcol[4];
        #pragma unroll
        for (int nt = 0; nt < 4; ++nt)
            bcol[nt] = (nt < 2) ? bqkv[K0 + wn * 32 + nt * 16 + l15]
                                : bqkv[V0 + wn * 32 + (nt - 2) * 16 + l15];
        #pragma unroll
        for (int mi = 0; mi < 8; ++mi)
            #pragma unroll
            for (int nt = 0; nt < 4; ++nt)
                #pragma unroll
                for (int rg = 0; rg < 4; ++rg) acc[mi][nt][rg] += bcol[nt];

        #pragma unroll
        for (int mi = 0; mi < 8; ++mi)
            #pragma unroll
            for (int rg = 0; rg < 4; ++rg) {
                float s = acc[mi][0][rg] * acc[mi][0][rg]
                        + acc[mi][1][rg] * acc[mi][1][rg];
                #pragma unroll
                for (int m = 1; m < 16; m <<= 1) s += __shfl_xor(s, m, 16);
                if (l15 == 0)
                    atomicAdd(&kssq[r0 + wm * 128 + mi * 16 + quad * 4 + rg], s);
            }

        #pragma unroll
        for (int mi = 0; mi < 8; ++mi)
            #pragma unroll
            for (int ntp = 0; ntp < 2; ++ntp) {
                int col = (by - 4) * 128 + wn * 32 + ntp * 16 + l15;
                #pragma unroll
                for (int rg = 0; rg < 4; ++rg) {
                    int row = r0 + wm * 128 + mi * 16 + quad * 4 + rg;
                    pb[(size_t)row * 1024 + col] =
                        f2bf(acc[mi][ntp][rg] * acc[mi][ntp + 2][rg]);
                }
            }
    }
}

// ---------------- Kernel 3: kv[b,d] = sum_t p[t,d]*rsqrt(kssq[t]) ----------------
__global__ void kv_reduce(const u16* __restrict__ pb, const float* __restrict__ kssq,
                          float* __restrict__ kv)
{
    int d  = threadIdx.x * 8;                  // 128 threads cover 1024 d
    int b  = blockIdx.y;                       // 0..3
    int t0 = blockIdx.x * 64;                  // 128 t-chunks of 64 rows
    float a[8];
    #pragma unroll
    for (int e = 0; e < 8; ++e) a[e] = 0.0f;
    for (int r = 0; r < 64; ++r) {
        int row = b * T_DIM + t0 + r;
        float kin = rsqrtf(kssq[row]);
        short8 p8 = *reinterpret_cast<const short8*>(pb + (size_t)row * 1024 + d);
        #pragma unroll
        for (int e = 0; e < 8; ++e)
            a[e] += bf2f((u16)p8[e]) * kin;
    }
    #pragma unroll
    for (int e = 0; e < 8; ++e)
        atomicAdd(&kv[b * D_DIM + d + e], a[e]);
}

// ---------------- Kernel 4: out = q*rsqrt(qssq)*kv*scale + bias (fp32) ----------------
__global__ void finalize(const u16* __restrict__ qb, const float* __restrict__ qssq,
                         const float* __restrict__ kv, const float* __restrict__ scale,
                         const float* __restrict__ bias, float* __restrict__ out)
{
    size_t idx = (size_t)blockIdx.x * 256 + threadIdx.x;   // vec8 index
    int row = (int)(idx >> 7);
    int dv  = ((int)idx & 127) * 8;
    int b   = row >> 13;
    float qi = rsqrtf(qssq[row]);
    short8 qv = *reinterpret_cast<const short8*>(qb + (size_t)row * D_DIM + dv);
    const float* kvp = kv + b * D_DIM + dv;
    const float* sp  = scale + dv;
    const float* bp  = bias + dv;
    float4 o0, o1;
    o0.x = bf2f((u16)qv[0]) * qi * kvp[0] * sp[0] + bp[0];
    o0.y = bf2f((u16)qv[1]) * qi * kvp[1] * sp[1] + bp[1];
    o0.z = bf2f((u16)qv[2]) * qi * kvp[2] * sp[2] + bp[2];
    o0.w = bf2f((u16)qv[3]) * qi * kvp[3] * sp[3] + bp[3];
    o1.x = bf2f((u16)qv[4]) * qi * kvp[4] * sp[4] + bp[4];
    o1.y = bf2f((u16)qv[5]) * qi * kvp[5] * sp[5] + bp[5];
    o1.z = bf2f((u16)qv[6]) * qi * kvp[6] * sp[6] + bp[6];
    o1.w = bf2f((u16)qv[7]) * qi * kvp[7] * sp[7] + bp[7];
    float* op = out + (size_t)row * D_DIM + dv;
    *reinterpret_cast<float4*>(op)     = o0;
    *reinterpret_cast<float4*>(op + 4) = o1;
}

extern "C" void kernel_launch(void* const* d_in, const int* in_sizes, int n_in,
                              void* d_out, int out_size, void* d_ws, size_t ws_size,
                              hipStream_t stream) {
    const float* x     = (const float*)d_in[0];
    const float* W     = (const float*)d_in[1];
    const float* bqkv  = (const float*)d_in[2];
    const float* scale = (const float*)d_in[3];
    const float* bias  = (const float*)d_in[4];
    float* out = (float*)d_out;

    // d_out doubles as scratch until finalize: xb (64 MB) + WT (6 MB) < 128 MB
    u16* xb = (u16*)d_out;
    u16* WT = (u16*)((char*)d_out + 67108864);

    char* ws = (char*)d_ws;
    u16*   qb   = (u16*)ws;                         //  67,108,864 B
    u16*   pb   = (u16*)(ws + 67108864);            //  67,108,864 B (k*v products)
    float* qssq = (float*)(ws + 134217728);         //     131,072 B
    float* kssq = (float*)(ws + 134348800);         //     131,072 B
    float* kv   = (float*)(ws + 134479872);         //      16,384 B
    // qssq|kssq|kv contiguous: 278,528 B = 68 blocks x 256 thr x 16 B zeroed in prep

    prep      <<<dim3(16384 + 3072 + 68), dim3(256), 0, stream>>>(x, xb, W, WT, qssq);
    gemm_k    <<<dim3(1536), dim3(512), 0, stream>>>(xb, WT, bqkv, qb, pb, qssq, kssq);
    kv_reduce <<<dim3(T_DIM / 64, 4), dim3(128), 0, stream>>>(pb, kssq, kv);
    finalize  <<<dim3(ROWS * (D_DIM / 8) / 256), dim3(256), 0, stream>>>(qb, qssq, kv, scale, bias, out);
}